// Round 3
// baseline (1574.057 us; speedup 1.0000x reference)
//
#include <hip/hip_runtime.h>
#include <hip/hip_bf16.h>

#define B_SZ    2
#define L_SEQ   2048
#define D_MODEL 384
#define D_INNER 768
#define D_STATE 16
#define DT_RANK 24
#define ML      (B_SZ * L_SEQ)   // 4096 rows

typedef __hip_bfloat16 bf16;
typedef __attribute__((ext_vector_type(8))) short bf16x8;
typedef __attribute__((ext_vector_type(4))) float f32x4;
typedef __attribute__((ext_vector_type(8))) float f32x8;

// ---------------------------------------------------------------------------
// MFMA bf16 GEMM over fp32 tensors: C(MxN) = A(MxK) * W(KxN), W fp32 row-major,
// A either fp32 (AF32=1) or bf16 (AF32=0) row-major. Inputs converted to bf16
// during LDS staging; fp32 accumulate.
// 256 thr / 4 waves; tile 64x64, BK=64; wave = 32x32 via 2x2 16x16x32 MFMA.
// A-frag: A[m=lane&15][k=(lane>>4)*8+j]; B-frag: B[n=lane&15][k=...]
// D: col=lane&15, row=(lane>>4)*4+reg  (m89/m91-verified)
// EPI 0: in_proj split -> outb0 = xp raw bf16 (n<768); outb1 = silu(z) bf16
// EPI 1: outf = fp32 C (ld=N, guard n<N)
// ---------------------------------------------------------------------------
template<int EPI, int AF32>
__global__ __launch_bounds__(256)
void gemm_mfma(const float* __restrict__ Af, const bf16* __restrict__ Ab,
               const float* __restrict__ W,
               bf16* __restrict__ outb0, bf16* __restrict__ outb1,
               float* __restrict__ outf, int M, int N, int K)
{
    __shared__ __attribute__((aligned(16))) short As[64][72];
    __shared__ __attribute__((aligned(16))) short Bs[64][72];
    const int tid  = threadIdx.x;
    const int lane = tid & 63;
    const int wave = tid >> 6;
    const int wm   = (wave & 1) * 32;
    const int wn   = (wave >> 1) * 32;
    const int m0   = blockIdx.y * 64;
    const int n0   = blockIdx.x * 64;

    f32x4 acc[2][2];
#pragma unroll
    for (int i = 0; i < 2; i++)
#pragma unroll
        for (int j = 0; j < 2; j++)
#pragma unroll
            for (int r = 0; r < 4; r++) acc[i][j][r] = 0.f;

    for (int kt = 0; kt < K; kt += 64) {
        __syncthreads();
        // Stage A tile 64x64 (512 8-elem chunks over 256 thr)
#pragma unroll
        for (int i = 0; i < 2; i++) {
            int c = tid + 256 * i;
            int m = c >> 3, k8 = (c & 7) * 8;
            if (AF32) {
                f32x8 a = *(const f32x8*)&Af[(size_t)(m0 + m) * K + kt + k8];
                bf16x8 h;
#pragma unroll
                for (int j = 0; j < 8; j++)
                    h[j] = (short)__bfloat16_as_ushort(__float2bfloat16(a[j]));
                *(bf16x8*)&As[m][k8] = h;
            } else {
                *(bf16x8*)&As[m][k8] =
                    *(const bf16x8*)&Ab[(size_t)(m0 + m) * K + kt + k8];
            }
        }
        // Stage W tile 64x64 transposed into Bs[n][k], fp32 -> bf16
#pragma unroll
        for (int i = 0; i < 2; i++) {
            int c = tid + 256 * i;
            int n8 = (c & 7) * 8, k = c >> 3;
            if (n0 + n8 + 8 <= N) {
                f32x8 w = *(const f32x8*)&W[(size_t)(kt + k) * N + n0 + n8];
#pragma unroll
                for (int j = 0; j < 8; j++)
                    Bs[n8 + j][k] = (short)__bfloat16_as_ushort(__float2bfloat16(w[j]));
            } else {
#pragma unroll
                for (int j = 0; j < 8; j++) Bs[n8 + j][k] = 0;
            }
        }
        __syncthreads();
#pragma unroll
        for (int ks = 0; ks < 2; ks++) {
            int kb = ks * 32 + (lane >> 4) * 8;
            bf16x8 a0 = *(const bf16x8*)&As[wm + (lane & 15)][kb];
            bf16x8 a1 = *(const bf16x8*)&As[wm + 16 + (lane & 15)][kb];
            bf16x8 b0 = *(const bf16x8*)&Bs[wn + (lane & 15)][kb];
            bf16x8 b1 = *(const bf16x8*)&Bs[wn + 16 + (lane & 15)][kb];
            acc[0][0] = __builtin_amdgcn_mfma_f32_16x16x32_bf16(a0, b0, acc[0][0], 0, 0, 0);
            acc[0][1] = __builtin_amdgcn_mfma_f32_16x16x32_bf16(a0, b1, acc[0][1], 0, 0, 0);
            acc[1][0] = __builtin_amdgcn_mfma_f32_16x16x32_bf16(a1, b0, acc[1][0], 0, 0, 0);
            acc[1][1] = __builtin_amdgcn_mfma_f32_16x16x32_bf16(a1, b1, acc[1][1], 0, 0, 0);
        }
    }

#pragma unroll
    for (int am = 0; am < 2; am++)
#pragma unroll
        for (int bn = 0; bn < 2; bn++)
#pragma unroll
            for (int r = 0; r < 4; r++) {
                int m = m0 + wm + am * 16 + (lane >> 4) * 4 + r;
                int n = n0 + wn + bn * 16 + (lane & 15);
                float v = acc[am][bn][r];
                if (EPI == 0) {
                    if (n < D_INNER)
                        outb0[(size_t)m * D_INNER + n] = __float2bfloat16(v);
                    else
                        outb1[(size_t)m * D_INNER + (n - D_INNER)] =
                            __float2bfloat16(v / (1.f + __expf(-v)));
                } else {
                    if (n < N) outf[(size_t)m * N + n] = v;
                }
            }
}

// ---------------------------------------------------------------------------
// Causal depthwise conv (K=4) + bias + SiLU; bf16 stream, fp32 weights/accum.
// ---------------------------------------------------------------------------
__global__ __launch_bounds__(256)
void conv_silu_kernel(const bf16* __restrict__ xp_raw,
                      const float* __restrict__ cw, const float* __restrict__ cb,
                      bf16* __restrict__ xp_out)
{
    int idx = blockIdx.x * 256 + threadIdx.x;           // ML*768 threads
    int d = idx % D_INNER;
    int ml = idx / D_INNER;
    int l = ml % L_SEQ;
    float s = cb[d];
#pragma unroll
    for (int j = 0; j < 4; j++) {
        int ls = l - 3 + j;
        if (ls >= 0)
            s += __bfloat162float(xp_raw[(size_t)(ml - 3 + j) * D_INNER + d]) * cw[d * 4 + j];
    }
    float act = s / (1.f + __expf(-s));                 // silu
    xp_out[idx] = __float2bfloat16(act);
}

// ---------------------------------------------------------------------------
// dt = softplus(dt_r @ dt_proj_w + b). K=24 (too small for MFMA). bf16 out.
// ---------------------------------------------------------------------------
__global__ __launch_bounds__(256)
void dt_kernel(const float* __restrict__ x_dbl, const float* __restrict__ dtw,
               const float* __restrict__ dtb, bf16* __restrict__ dt)
{
    int idx = blockIdx.x * 256 + threadIdx.x;           // ML*768 threads
    int d = idx % D_INNER;
    int m = idx / D_INNER;
    float acc = dtb[d];
    const float* xr = &x_dbl[(size_t)m * 56];
#pragma unroll
    for (int r = 0; r < DT_RANK; r++)
        acc += xr[r] * dtw[r * D_INNER + d];
    float sp = fmaxf(acc, 0.f) + log1pf(__expf(-fabsf(acc)));
    dt[idx] = __float2bfloat16(sp);
}

// ---------------------------------------------------------------------------
// Selective scan: 16 lanes per (b,d), lane n owns h[n].
// h = exp(dt*A[n])*h + B[n]*(dt*xp); y = shfl-reduce(h*C[n]);
// epilogue y = (y + xp*D) * silu_z; bf16 store.
// ---------------------------------------------------------------------------
__global__ __launch_bounds__(256)
void scan_kernel(const bf16* __restrict__ dt, const bf16* __restrict__ xp,
                 const float* __restrict__ x_dbl, const bf16* __restrict__ zs,
                 const float* __restrict__ A_log, const float* __restrict__ Dp,
                 bf16* __restrict__ y_out)
{
    const int tid = threadIdx.x;
    const int g = blockIdx.x * 16 + (tid >> 4);         // 0..1535 = (b,d)
    const int n = tid & 15;
    const int b = g / D_INNER;
    const int d = g % D_INNER;
    const float A = -__expf(A_log[d * D_STATE + n]);
    const float Dd = Dp[d];
    float h = 0.f;
    const size_t base = (size_t)b * L_SEQ;
    for (int l = 0; l < L_SEQ; l++) {
        size_t m = base + l;
        float dtv = __bfloat162float(dt[m * D_INNER + d]);
        float xpv = __bfloat162float(xp[m * D_INNER + d]);
        float Bn = x_dbl[m * 56 + DT_RANK + n];
        float Cn = x_dbl[m * 56 + DT_RANK + D_STATE + n];
        h = __expf(dtv * A) * h + Bn * (dtv * xpv);
        float yv = h * Cn;
        yv += __shfl_xor(yv, 1);
        yv += __shfl_xor(yv, 2);
        yv += __shfl_xor(yv, 4);
        yv += __shfl_xor(yv, 8);
        if (n == 0) {
            float y = (yv + xpv * Dd) * __bfloat162float(zs[m * D_INNER + d]);
            y_out[m * D_INNER + d] = __float2bfloat16(y);
        }
    }
}

// ---------------------------------------------------------------------------
extern "C" void kernel_launch(void* const* d_in, const int* in_sizes, int n_in,
                              void* d_out, int out_size, void* d_ws, size_t ws_size,
                              hipStream_t stream)
{
    const float* x         = (const float*)d_in[0];
    const float* in_proj_w = (const float*)d_in[1];
    const float* conv_w    = (const float*)d_in[2];
    const float* conv_b    = (const float*)d_in[3];
    const float* x_proj_w  = (const float*)d_in[4];
    const float* dt_proj_w = (const float*)d_in[5];
    const float* dt_proj_b = (const float*)d_in[6];
    const float* A_log     = (const float*)d_in[7];
    const float* Dvec      = (const float*)d_in[8];
    const float* out_proj_w= (const float*)d_in[9];

    // workspace: 4x bf16 [ML*768] + fp32 [ML*56]  = ~26.1 MB
    bf16* xp_raw_bf = (bf16*)d_ws;                       // ML*768 (reused as y)
    bf16* zs_bf     = xp_raw_bf + (size_t)ML * D_INNER;  // ML*768 silu(z)
    bf16* xp_b16    = zs_bf     + (size_t)ML * D_INNER;  // ML*768
    bf16* dt_bf     = xp_b16    + (size_t)ML * D_INNER;  // ML*768
    float* x_dbl    = (float*)(dt_bf + (size_t)ML * D_INNER); // ML*56 fp32
    bf16* y_b16     = xp_raw_bf;                         // alias (dead after conv)

    dim3 blk(256);

    // 1) in_proj: (4096x384 f32)*(384x1536 f32) -> xp_raw_bf | silu(z) bf16
    gemm_mfma<0, 1><<<dim3(2 * D_INNER / 64, ML / 64), blk, 0, stream>>>(
        x, nullptr, in_proj_w, xp_raw_bf, zs_bf, nullptr, ML, 2 * D_INNER, D_MODEL);

    // 2) depthwise causal conv + silu
    conv_silu_kernel<<<(ML * D_INNER) / 256, blk, 0, stream>>>(
        xp_raw_bf, conv_w, conv_b, xp_b16);

    // 3) x_proj: (4096x768 bf16)*(768x56 f32) -> x_dbl fp32
    gemm_mfma<1, 0><<<dim3(1, ML / 64), blk, 0, stream>>>(
        nullptr, xp_b16, x_proj_w, nullptr, nullptr, x_dbl, ML, 56, D_INNER);

    // 4) dt_proj + softplus -> bf16
    dt_kernel<<<(ML * D_INNER) / 256, blk, 0, stream>>>(
        x_dbl, dt_proj_w, dt_proj_b, dt_bf);

    // 5) selective scan + epilogue -> y bf16 (aliases xp_raw_bf)
    scan_kernel<<<(B_SZ * D_INNER) / 16, blk, 0, stream>>>(
        dt_bf, xp_b16, x_dbl, zs_bf, A_log, Dvec, y_b16);

    // 6) out_proj: (4096x768 bf16)*(768x384 f32) -> d_out fp32
    gemm_mfma<1, 0><<<dim3(D_MODEL / 64, ML / 64), blk, 0, stream>>>(
        nullptr, y_b16, out_proj_w, nullptr, nullptr, (float*)d_out, ML, D_MODEL, D_INNER);
}

// Round 4
// 528.834 us; speedup vs baseline: 2.9765x; 2.9765x over previous
//
#include <hip/hip_runtime.h>
#include <hip/hip_bf16.h>

#define B_SZ    2
#define L_SEQ   2048
#define D_MODEL 384
#define D_INNER 768
#define D_STATE 16
#define DT_RANK 24
#define ML      (B_SZ * L_SEQ)   // 4096 rows
#define NCHUNK  64
#define CHLEN   (L_SEQ / NCHUNK) // 32

typedef __hip_bfloat16 bf16;
typedef __attribute__((ext_vector_type(8))) short bf16x8;
typedef __attribute__((ext_vector_type(4))) float f32x4;
typedef __attribute__((ext_vector_type(8))) float f32x8;

// ---------------------------------------------------------------------------
// MFMA bf16 GEMM over fp32 tensors: C(MxN) = A(MxK) * W(KxN), W fp32 row-major,
// A either fp32 (AF32=1) or bf16 (AF32=0) row-major. Inputs converted to bf16
// during LDS staging; fp32 accumulate.
// 256 thr / 4 waves; tile 64x64, BK=64; wave = 32x32 via 2x2 16x16x32 MFMA.
// A-frag: A[m=lane&15][k=(lane>>4)*8+j]; B-frag: B[n=lane&15][k=...]
// D: col=lane&15, row=(lane>>4)*4+reg  (m89/m91-verified)
// EPI 0: in_proj split -> outb0 = xp raw bf16 (n<768); outb1 = silu(z) bf16
// EPI 1: outf = fp32 C (ld=N, guard n<N)
// ---------------------------------------------------------------------------
template<int EPI, int AF32>
__global__ __launch_bounds__(256)
void gemm_mfma(const float* __restrict__ Af, const bf16* __restrict__ Ab,
               const float* __restrict__ W,
               bf16* __restrict__ outb0, bf16* __restrict__ outb1,
               float* __restrict__ outf, int M, int N, int K)
{
    __shared__ __attribute__((aligned(16))) short As[64][72];
    __shared__ __attribute__((aligned(16))) short Bs[64][72];
    const int tid  = threadIdx.x;
    const int lane = tid & 63;
    const int wave = tid >> 6;
    const int wm   = (wave & 1) * 32;
    const int wn   = (wave >> 1) * 32;
    const int m0   = blockIdx.y * 64;
    const int n0   = blockIdx.x * 64;

    f32x4 acc[2][2];
#pragma unroll
    for (int i = 0; i < 2; i++)
#pragma unroll
        for (int j = 0; j < 2; j++)
#pragma unroll
            for (int r = 0; r < 4; r++) acc[i][j][r] = 0.f;

    for (int kt = 0; kt < K; kt += 64) {
        __syncthreads();
        // Stage A tile 64x64 (512 8-elem chunks over 256 thr)
#pragma unroll
        for (int i = 0; i < 2; i++) {
            int c = tid + 256 * i;
            int m = c >> 3, k8 = (c & 7) * 8;
            if (AF32) {
                f32x8 a = *(const f32x8*)&Af[(size_t)(m0 + m) * K + kt + k8];
                bf16x8 h;
#pragma unroll
                for (int j = 0; j < 8; j++)
                    h[j] = (short)__bfloat16_as_ushort(__float2bfloat16(a[j]));
                *(bf16x8*)&As[m][k8] = h;
            } else {
                *(bf16x8*)&As[m][k8] =
                    *(const bf16x8*)&Ab[(size_t)(m0 + m) * K + kt + k8];
            }
        }
        // Stage W tile 64x64 transposed into Bs[n][k], fp32 -> bf16
#pragma unroll
        for (int i = 0; i < 2; i++) {
            int c = tid + 256 * i;
            int n8 = (c & 7) * 8, k = c >> 3;
            if (n0 + n8 + 8 <= N) {
                f32x8 w = *(const f32x8*)&W[(size_t)(kt + k) * N + n0 + n8];
#pragma unroll
                for (int j = 0; j < 8; j++)
                    Bs[n8 + j][k] = (short)__bfloat16_as_ushort(__float2bfloat16(w[j]));
            } else {
#pragma unroll
                for (int j = 0; j < 8; j++) Bs[n8 + j][k] = 0;
            }
        }
        __syncthreads();
#pragma unroll
        for (int ks = 0; ks < 2; ks++) {
            int kb = ks * 32 + (lane >> 4) * 8;
            bf16x8 a0 = *(const bf16x8*)&As[wm + (lane & 15)][kb];
            bf16x8 a1 = *(const bf16x8*)&As[wm + 16 + (lane & 15)][kb];
            bf16x8 b0 = *(const bf16x8*)&Bs[wn + (lane & 15)][kb];
            bf16x8 b1 = *(const bf16x8*)&Bs[wn + 16 + (lane & 15)][kb];
            acc[0][0] = __builtin_amdgcn_mfma_f32_16x16x32_bf16(a0, b0, acc[0][0], 0, 0, 0);
            acc[0][1] = __builtin_amdgcn_mfma_f32_16x16x32_bf16(a0, b1, acc[0][1], 0, 0, 0);
            acc[1][0] = __builtin_amdgcn_mfma_f32_16x16x32_bf16(a1, b0, acc[1][0], 0, 0, 0);
            acc[1][1] = __builtin_amdgcn_mfma_f32_16x16x32_bf16(a1, b1, acc[1][1], 0, 0, 0);
        }
    }

#pragma unroll
    for (int am = 0; am < 2; am++)
#pragma unroll
        for (int bn = 0; bn < 2; bn++)
#pragma unroll
            for (int r = 0; r < 4; r++) {
                int m = m0 + wm + am * 16 + (lane >> 4) * 4 + r;
                int n = n0 + wn + bn * 16 + (lane & 15);
                float v = acc[am][bn][r];
                if (EPI == 0) {
                    if (n < D_INNER)
                        outb0[(size_t)m * D_INNER + n] = __float2bfloat16(v);
                    else
                        outb1[(size_t)m * D_INNER + (n - D_INNER)] =
                            __float2bfloat16(v / (1.f + __expf(-v)));
                } else {
                    if (n < N) outf[(size_t)m * N + n] = v;
                }
            }
}

// ---------------------------------------------------------------------------
// Causal depthwise conv (K=4) + bias + SiLU; bf16 stream, fp32 weights/accum.
// ---------------------------------------------------------------------------
__global__ __launch_bounds__(256)
void conv_silu_kernel(const bf16* __restrict__ xp_raw,
                      const float* __restrict__ cw, const float* __restrict__ cb,
                      bf16* __restrict__ xp_out)
{
    int idx = blockIdx.x * 256 + threadIdx.x;           // ML*768 threads
    int d = idx % D_INNER;
    int ml = idx / D_INNER;
    int l = ml % L_SEQ;
    float s = cb[d];
#pragma unroll
    for (int j = 0; j < 4; j++) {
        int ls = l - 3 + j;
        if (ls >= 0)
            s += __bfloat162float(xp_raw[(size_t)(ml - 3 + j) * D_INNER + d]) * cw[d * 4 + j];
    }
    float act = s / (1.f + __expf(-s));                 // silu
    xp_out[idx] = __float2bfloat16(act);
}

// ---------------------------------------------------------------------------
// dt = softplus(dt_r @ dt_proj_w + b). K=24 (too small for MFMA). bf16 out.
// ---------------------------------------------------------------------------
__global__ __launch_bounds__(256)
void dt_kernel(const float* __restrict__ x_dbl, const float* __restrict__ dtw,
               const float* __restrict__ dtb, bf16* __restrict__ dt)
{
    int idx = blockIdx.x * 256 + threadIdx.x;           // ML*768 threads
    int d = idx % D_INNER;
    int m = idx / D_INNER;
    float acc = dtb[d];
    const float* xr = &x_dbl[(size_t)m * 56];
#pragma unroll
    for (int r = 0; r < DT_RANK; r++)
        acc += xr[r] * dtw[r * D_INNER + d];
    float sp = fmaxf(acc, 0.f) + log1pf(__expf(-fabsf(acc)));
    dt[idx] = __float2bfloat16(sp);
}

// ---------------------------------------------------------------------------
// Chunk-parallel selective scan. One 1024-thr block per (b,d).
// thread = (chunk c = tid>>4, state n = tid&15); 64 chunks x 32 steps.
// Phase 1: local scan from h=0, stash (a_j,u_j) in regs, emit (P, h_end).
// Phase 2: Kogge-Stone scan over chunks in LDS composing (P,h).
// Phase 3: re-scan from H_init; y = shfl-reduce(h*C); fused epilogue.
// ---------------------------------------------------------------------------
__global__ __launch_bounds__(1024)
void scan_kernel(const bf16* __restrict__ dt, const bf16* __restrict__ xp,
                 const float* __restrict__ x_dbl, const bf16* __restrict__ zs,
                 const float* __restrict__ A_log, const float* __restrict__ Dp,
                 bf16* __restrict__ y_out)
{
    __shared__ float sP[NCHUNK][D_STATE];
    __shared__ float sH[NCHUNK][D_STATE];
    const int tid = threadIdx.x;
    const int c = tid >> 4;           // chunk 0..63
    const int n = tid & 15;           // state 0..15
    const int g = blockIdx.x;         // (b,d)
    const int b = g / D_INNER;
    const int d = g % D_INNER;
    const float A = -__expf(A_log[d * D_STATE + n]);
    const size_t base = (size_t)b * L_SEQ + (size_t)c * CHLEN;

    float a[CHLEN], u[CHLEN];
    float h = 0.f, P = 1.f;
#pragma unroll
    for (int j = 0; j < CHLEN; j++) {
        size_t m = base + j;
        float dtv = __bfloat162float(dt[m * D_INNER + d]);
        float xpv = __bfloat162float(xp[m * D_INNER + d]);
        float Bn  = x_dbl[m * 56 + DT_RANK + n];
        float aj = __expf(dtv * A);
        float uj = Bn * (dtv * xpv);
        a[j] = aj; u[j] = uj;
        h = aj * h + uj;
        P *= aj;
    }
    sP[c][n] = P;
    sH[c][n] = h;
    __syncthreads();

    // Kogge-Stone inclusive scan over chunks: compose (P,h) pairs
#pragma unroll
    for (int s = 1; s < NCHUNK; s <<= 1) {
        float p2 = 0.f, h2 = 0.f;
        const bool act = (c >= s);
        if (act) { p2 = sP[c - s][n]; h2 = sH[c - s][n]; }
        __syncthreads();
        if (act) {
            sH[c][n] = sP[c][n] * h2 + sH[c][n];
            sP[c][n] = sP[c][n] * p2;
        }
        __syncthreads();
    }
    const float hinit = (c == 0) ? 0.f : sH[c - 1][n];

    // Phase 3: corrected re-scan + output
    const float Dd = Dp[d];
    h = hinit;
#pragma unroll
    for (int j = 0; j < CHLEN; j++) {
        size_t m = base + j;
        h = a[j] * h + u[j];
        float Cn = x_dbl[m * 56 + DT_RANK + D_STATE + n];
        float yv = h * Cn;
        yv += __shfl_xor(yv, 1);
        yv += __shfl_xor(yv, 2);
        yv += __shfl_xor(yv, 4);
        yv += __shfl_xor(yv, 8);
        if (n == 0) {
            float xpv = __bfloat162float(xp[m * D_INNER + d]);
            float y = (yv + xpv * Dd) * __bfloat162float(zs[m * D_INNER + d]);
            y_out[m * D_INNER + d] = __float2bfloat16(y);
        }
    }
}

// ---------------------------------------------------------------------------
extern "C" void kernel_launch(void* const* d_in, const int* in_sizes, int n_in,
                              void* d_out, int out_size, void* d_ws, size_t ws_size,
                              hipStream_t stream)
{
    const float* x         = (const float*)d_in[0];
    const float* in_proj_w = (const float*)d_in[1];
    const float* conv_w    = (const float*)d_in[2];
    const float* conv_b    = (const float*)d_in[3];
    const float* x_proj_w  = (const float*)d_in[4];
    const float* dt_proj_w = (const float*)d_in[5];
    const float* dt_proj_b = (const float*)d_in[6];
    const float* A_log     = (const float*)d_in[7];
    const float* Dvec      = (const float*)d_in[8];
    const float* out_proj_w= (const float*)d_in[9];

    // workspace: 4x bf16 [ML*768] + fp32 [ML*56]  = ~26.1 MB
    bf16* xp_raw_bf = (bf16*)d_ws;                       // ML*768 (reused as y)
    bf16* zs_bf     = xp_raw_bf + (size_t)ML * D_INNER;  // ML*768 silu(z)
    bf16* xp_b16    = zs_bf     + (size_t)ML * D_INNER;  // ML*768
    bf16* dt_bf     = xp_b16    + (size_t)ML * D_INNER;  // ML*768
    float* x_dbl    = (float*)(dt_bf + (size_t)ML * D_INNER); // ML*56 fp32
    bf16* y_b16     = xp_raw_bf;                         // alias (dead after conv)

    dim3 blk(256);

    // 1) in_proj: (4096x384 f32)*(384x1536 f32) -> xp_raw_bf | silu(z) bf16
    gemm_mfma<0, 1><<<dim3(2 * D_INNER / 64, ML / 64), blk, 0, stream>>>(
        x, nullptr, in_proj_w, xp_raw_bf, zs_bf, nullptr, ML, 2 * D_INNER, D_MODEL);

    // 2) depthwise causal conv + silu
    conv_silu_kernel<<<(ML * D_INNER) / 256, blk, 0, stream>>>(
        xp_raw_bf, conv_w, conv_b, xp_b16);

    // 3) x_proj: (4096x768 bf16)*(768x56 f32) -> x_dbl fp32
    gemm_mfma<1, 0><<<dim3(1, ML / 64), blk, 0, stream>>>(
        nullptr, xp_b16, x_proj_w, nullptr, nullptr, x_dbl, ML, 56, D_INNER);

    // 4) dt_proj + softplus -> bf16
    dt_kernel<<<(ML * D_INNER) / 256, blk, 0, stream>>>(
        x_dbl, dt_proj_w, dt_proj_b, dt_bf);

    // 5) chunk-parallel selective scan + epilogue -> y bf16 (aliases xp_raw_bf)
    scan_kernel<<<B_SZ * D_INNER, 1024, 0, stream>>>(
        dt_bf, xp_b16, x_dbl, zs_bf, A_log, Dvec, y_b16);

    // 6) out_proj: (4096x768 bf16)*(768x384 f32) -> d_out fp32
    gemm_mfma<1, 0><<<dim3(D_MODEL / 64, ML / 64), blk, 0, stream>>>(
        nullptr, y_b16, out_proj_w, nullptr, nullptr, (float*)d_out, ML, D_MODEL, D_INNER);
}